// Round 4
// baseline (537.966 us; speedup 1.0000x reference)
//
#include <hip/hip_runtime.h>
#include <cstdint>
#include <cstddef>

typedef __bf16 bf16x8 __attribute__((ext_vector_type(8)));
typedef float f32x4 __attribute__((ext_vector_type(4)));
typedef unsigned short u16;
typedef u16 u16x4 __attribute__((ext_vector_type(4)));
typedef u16 u16x8 __attribute__((ext_vector_type(8)));

// fp32 -> bf16 round-to-nearest-even
__device__ __forceinline__ u16 f2bf(float f) {
  union { float f; unsigned u; } v; v.f = f;
  return (u16)((v.u + 0x7FFFu + ((v.u >> 16) & 1u)) >> 16);
}

__device__ __forceinline__ void cvt_wr(u16* dst, float4 v) {
  const u16x4 d = { f2bf(v.x), f2bf(v.y), f2bf(v.z), f2bf(v.w) };
  *(u16x4*)dst = d;
}

// nontemporal float4 load (x0 is single-use streaming data)
__device__ __forceinline__ float4 ntld(const float* p) {
  f32x4 v = __builtin_nontemporal_load((const f32x4*)p);
  union { f32x4 a; float4 b; } u; u.a = v;
  return u.b;
}

// ---------------------------------------------------------------------------
// Pre-pass: fp32 -> bf16 + MFMA *fragment-major* layout, SOURCE-indexed.
// If sel != null: convert plane s only if s appears in sel[0..31] (route dedup).
// out[(((s*NB + nb)*KT + kt)*64 + l)*8 + e] = in[s][kt*32 + (l>>4)*8 + e][nb*16 + (l&15)]
// ---------------------------------------------------------------------------
__global__ void frag_cvt(const float* __restrict__ in, const int* __restrict__ sel,
                         u16* __restrict__ out, int K, int N) {
  const int s = blockIdx.z;
  if (sel) {
    bool need = false;
#pragma unroll
    for (int i = 0; i < 32; ++i) need |= (sel[i] == s);
    if (!need) return;
  }
  const int f = threadIdx.x >> 6, l = threadIdx.x & 63;
  const int r = l & 15, q = l >> 4;
  const int kt = blockIdx.x * 4 + f;
  const int nb = blockIdx.y;
  const int KT = K >> 5, NB = N >> 4;
  const float* ip = in + (size_t)s * K * N + (size_t)(kt * 32 + q * 8) * N + nb * 16 + r;
  u16x8 d;
#pragma unroll
  for (int e = 0; e < 8; ++e) d[e] = f2bf(ip[(size_t)e * N]);
  *(u16x8*)&out[((((size_t)s * NB + nb) * KT + kt) * 64 + l) * 8] = d;
}

// relu + bias epilogue -> frag-major Xs.
// lane (r,q) acc[mt][nt] holds X[mt*16+r][wn*32 + nt*16 + q*4 + j]; kt-slice = wn.
__device__ __forceinline__ void epi_relu(u16* __restrict__ Xs, const float* __restrict__ bias,
                                         f32x4 acc[8][2], int wn, int r, int q) {
#pragma unroll
  for (int mt = 0; mt < 8; ++mt) {
#pragma unroll
    for (int nt = 0; nt < 2; ++nt) {
      const int col = wn * 32 + nt * 16 + q * 4;
      const int q2 = (col >> 3) & 3;
      const float4 bb = *(const float4*)&bias[col];
      const f32x4 v = acc[mt][nt];
      const u16x4 d = { f2bf(fmaxf(v.x + bb.x, 0.f)), f2bf(fmaxf(v.y + bb.y, 0.f)),
                        f2bf(fmaxf(v.z + bb.z, 0.f)), f2bf(fmaxf(v.w + bb.w, 0.f)) };
      *(u16x4*)&Xs[((wn * 8 + mt) * 64 + q2 * 16 + r) * 8 + (q & 1) * 4] = d;
    }
  }
}

// ---------------------------------------------------------------------------
// Fused 3-layer MLP per (128-row batch tile, agent). 1024 threads / 16 waves.
// Xs: 128 KB frag-major [kt 16][MT 8][lane 64][e 8] (x0 -> X1 -> h in place).
// Wave wn: FULL M=128, n-slice 32 (acc[8][2]).
// Phase 1: x0 conversion fused, 4-deep static register pipeline (vb[4]),
//   B loaded per-kt with no prefetch regs (bubble hides in x0-rate slack).
//   Peak regs ~114 < 128 (4 waves/SIMD without spill).
// Phase 2/3: barrier-free k-loops, 1-deep B prefetch.
// ---------------------------------------------------------------------------
__global__ __launch_bounds__(1024, 4)
void fused_mlp(const float* __restrict__ X0, const u16* __restrict__ Wsf,
               const float* __restrict__ bsh, const u16* __restrict__ W1f,
               const float* __restrict__ b1, const u16* __restrict__ W2f,
               const float* __restrict__ b2, const int* __restrict__ route,
               float* __restrict__ Out) {
  __shared__ u16 Xs[65536];                  // 128 KB

  const int tid = threadIdx.x;
  const int w = tid >> 6, l = tid & 63;
  const int r = l & 15, q = l >> 4;
  const int wn = w;                          // n-slice of 32

  // XCD-pinned: agent a on xcd = a>>2 (distinct-expert set <= 2 MB per L2)
  const int bid = blockIdx.x;                // 1024 blocks, 1024 % 8 == 0
  const int xcd = bid & 7, idx = bid >> 3;   // idx 0..127 per xcd
  const int a = (xcd << 2) | (idx >> 5);
  const int b0 = (idx & 31) << 7;            // 128-row tile
  const int rt = route[a];

  // x0 staging map: thread -> (row sm, col-quad scq); per kt-slice one float4.
  const int sm = tid >> 3, scq = tid & 7;
  const float* gx = X0 + (((size_t)(b0 + sm) * 32 + a) << 9) + (scq << 2);
  const int sdst = (((sm >> 4) << 6) + ((scq >> 1) << 4) + (sm & 15)) * 8 + (scq & 1) * 4;

  const u16* Af = Xs + l * 8;                // A frag: + kt*4096 + mt*512
  const u16* Bw = Wsf + (wn << 14) + l * 8;  // nb = 2*wn + nt: nt stride 8192, kt stride 512

  f32x4 acc[8][2];
#pragma unroll
  for (int mt = 0; mt < 8; ++mt)
#pragma unroll
    for (int nt = 0; nt < 2; ++nt) acc[mt][nt] = (f32x4){0.f, 0.f, 0.f, 0.f};

  // ========== phase 1 (x0 conversion fused, 4-deep pipeline) ==========
  float4 vb[4];                              // slice s in vb[s & 3]; all indices static
  vb[0] = ntld(gx);
  vb[1] = ntld(gx + 32);
  vb[2] = ntld(gx + 64);
  vb[3] = ntld(gx + 96);
  cvt_wr(&Xs[sdst], vb[0]);                  // write slice 0
  __syncthreads();

#pragma unroll
  for (int kt = 0; kt < 16; ++kt) {
    if (kt < 12) vb[kt & 3] = ntld(gx + (kt + 4) * 32);   // slice kt+4 (slot free: slice kt already in LDS)
    const bf16x8 bc0 = *(const bf16x8*)(Bw + kt * 512);
    const bf16x8 bc1 = *(const bf16x8*)(Bw + 8192 + kt * 512);
#pragma unroll
    for (int mt = 0; mt < 8; ++mt) {
      const bf16x8 af = *(const bf16x8*)(Af + kt * 4096 + mt * 512);
      acc[mt][0] = __builtin_amdgcn_mfma_f32_16x16x32_bf16(bc0, af, acc[mt][0], 0, 0, 0);
      acc[mt][1] = __builtin_amdgcn_mfma_f32_16x16x32_bf16(bc1, af, acc[mt][1], 0, 0, 0);
    }
    if (kt < 15) {                           // write slice kt+1 (loaded 4 kt ago), then sync
      cvt_wr(&Xs[(kt + 1) * 4096 + sdst], vb[(kt + 1) & 3]);
      __syncthreads();
    }
  }
  __syncthreads();                           // all x0 reads done

  // hoist phase-2 first B pair: lands under phase-1 epilogue VALU
  const u16* B1 = W1f + ((size_t)rt << 18) + (wn << 14) + l * 8;
  bf16x8 bc0 = *(const bf16x8*)(B1);
  bf16x8 bc1 = *(const bf16x8*)(B1 + 8192);

  epi_relu(Xs, bsh, acc, wn, r, q);
  __syncthreads();                           // X1 visible

  // ========== phase 2: h = relu(X1 @ W1[rt]^T + b1[rt]) ==========
#pragma unroll
  for (int mt = 0; mt < 8; ++mt)
#pragma unroll
    for (int nt = 0; nt < 2; ++nt) acc[mt][nt] = (f32x4){0.f, 0.f, 0.f, 0.f};
#pragma unroll
  for (int kt = 0; kt < 16; ++kt) {
    bf16x8 bn0, bn1;
    if (kt < 15) {
      bn0 = *(const bf16x8*)(B1 + (kt + 1) * 512);
      bn1 = *(const bf16x8*)(B1 + 8192 + (kt + 1) * 512);
    }
#pragma unroll
    for (int mt = 0; mt < 8; ++mt) {
      const bf16x8 af = *(const bf16x8*)(Af + kt * 4096 + mt * 512);
      acc[mt][0] = __builtin_amdgcn_mfma_f32_16x16x32_bf16(bc0, af, acc[mt][0], 0, 0, 0);
      acc[mt][1] = __builtin_amdgcn_mfma_f32_16x16x32_bf16(bc1, af, acc[mt][1], 0, 0, 0);
    }
    bc0 = bn0; bc1 = bn1;
  }
  __syncthreads();                           // all X1 reads done
  epi_relu(Xs, b1 + (size_t)rt * 512, acc, wn, r, q);
  __syncthreads();                           // h visible

  // ========== phase 3: out = h @ W2[rt]^T + b2[rt] ==========
  {
    const int mtg = w >> 1, nt3 = w & 1;     // 128x32 out = 16 frags, 1 per wave
    const u16* Ah = Xs + (mtg << 9) + l * 8;
    const u16* B2 = W2f + ((size_t)rt << 14) + (nt3 << 13) + l * 8;
    f32x4 o = (f32x4){0.f, 0.f, 0.f, 0.f};
#pragma unroll
    for (int kt = 0; kt < 16; ++kt) {
      const bf16x8 af = *(const bf16x8*)(Ah + kt * 4096);
      const bf16x8 bf = *(const bf16x8*)(B2 + kt * 512);
      o = __builtin_amdgcn_mfma_f32_16x16x32_bf16(bf, af, o, 0, 0, 0);
    }
    const int col = (nt3 << 4) + (q << 2);
    const float4 bb = *(const float4*)&b2[rt * 32 + col];
    const float4 res = { o.x + bb.x, o.y + bb.y, o.z + bb.z, o.w + bb.w };
    *(float4*)&Out[(size_t)(b0 + (mtg << 4) + r) * 1024 + a * 32 + col] = res;
  }
}

// ---------------------------------------------------------------------------
extern "C" void kernel_launch(void* const* d_in, const int* in_sizes, int n_in,
                              void* d_out, int out_size, void* d_ws, size_t ws_size,
                              hipStream_t stream) {
  (void)in_sizes; (void)n_in; (void)out_size; (void)ws_size;
  const float* x0  = (const float*)d_in[0];
  const float* Wsh = (const float*)d_in[1];
  const float* bsh = (const float*)d_in[2];
  const float* W1  = (const float*)d_in[3];
  const float* b1  = (const float*)d_in[4];
  const float* W2  = (const float*)d_in[5];
  const float* b2  = (const float*)d_in[6];
  const int* route = (const int*)d_in[7];
  float* out = (float*)d_out;

  char* ws = (char*)d_ws;
  u16* Wsf = (u16*)(ws + 0);                      // 512*512*2    = 512 KB  frag-major
  u16* W1f = (u16*)(ws + 524288);                 // 32*512*512*2 = 16 MB   frag-major, source-indexed
  u16* W2f = (u16*)(ws + 524288 + 16777216);      // 32*32*512*2  = 1 MB    frag-major, source-indexed

  frag_cvt<<<dim3(4, 32, 1),  256, 0, stream>>>(Wsh, nullptr, Wsf, 512, 512);
  frag_cvt<<<dim3(4, 32, 32), 256, 0, stream>>>(W1, route, W1f, 512, 512);   // only used experts
  frag_cvt<<<dim3(4, 2, 32),  256, 0, stream>>>(W2, route, W2f, 512, 32);    // only used experts
  fused_mlp<<<dim3(1024), 1024, 0, stream>>>(x0, Wsf, bsh, W1f, b1, W2f, b2, route, out);
}

// Round 5
// 520.180 us; speedup vs baseline: 1.0342x; 1.0342x over previous
//
#include <hip/hip_runtime.h>
#include <cstdint>
#include <cstddef>

typedef __bf16 bf16x8 __attribute__((ext_vector_type(8)));
typedef float f32x4 __attribute__((ext_vector_type(4)));
typedef unsigned short u16;
typedef u16 u16x4 __attribute__((ext_vector_type(4)));
typedef u16 u16x8 __attribute__((ext_vector_type(8)));

// fp32 -> bf16 round-to-nearest-even
__device__ __forceinline__ u16 f2bf(float f) {
  union { float f; unsigned u; } v; v.f = f;
  return (u16)((v.u + 0x7FFFu + ((v.u >> 16) & 1u)) >> 16);
}

__device__ __forceinline__ void cvt_wr(u16* dst, float4 v) {
  const u16x4 d = { f2bf(v.x), f2bf(v.y), f2bf(v.z), f2bf(v.w) };
  *(u16x4*)dst = d;
}

// nontemporal float4 load (x0 is single-use streaming data)
__device__ __forceinline__ float4 ntld(const float* p) {
  f32x4 v = __builtin_nontemporal_load((const f32x4*)p);
  union { f32x4 a; float4 b; } u; u.a = v;
  return u.b;
}

// ---------------------------------------------------------------------------
// Pre-pass: fp32 -> bf16 + MFMA *fragment-major* layout, SOURCE-indexed.
// If sel != null: convert plane s only if s appears in sel[0..31] (route dedup).
// out[(((s*NB + nb)*KT + kt)*64 + l)*8 + e] = in[s][kt*32 + (l>>4)*8 + e][nb*16 + (l&15)]
// ---------------------------------------------------------------------------
__global__ void frag_cvt(const float* __restrict__ in, const int* __restrict__ sel,
                         u16* __restrict__ out, int K, int N) {
  const int s = blockIdx.z;
  if (sel) {
    bool need = false;
#pragma unroll
    for (int i = 0; i < 32; ++i) need |= (sel[i] == s);
    if (!need) return;
  }
  const int f = threadIdx.x >> 6, l = threadIdx.x & 63;
  const int r = l & 15, q = l >> 4;
  const int kt = blockIdx.x * 4 + f;
  const int nb = blockIdx.y;
  const int KT = K >> 5, NB = N >> 4;
  const float* ip = in + (size_t)s * K * N + (size_t)(kt * 32 + q * 8) * N + nb * 16 + r;
  u16x8 d;
#pragma unroll
  for (int e = 0; e < 8; ++e) d[e] = f2bf(ip[(size_t)e * N]);
  *(u16x8*)&out[((((size_t)s * NB + nb) * KT + kt) * 64 + l) * 8] = d;
}

// relu + bias epilogue -> frag-major Xs.
// lane (r,q) acc[mt][nt] holds X[mt*16+r][wn*32 + nt*16 + q*4 + j]; kt-slice = wn.
__device__ __forceinline__ void epi_relu(u16* __restrict__ Xs, const float* __restrict__ bias,
                                         f32x4 acc[8][2], int wn, int r, int q) {
#pragma unroll
  for (int mt = 0; mt < 8; ++mt) {
#pragma unroll
    for (int nt = 0; nt < 2; ++nt) {
      const int col = wn * 32 + nt * 16 + q * 4;
      const int q2 = (col >> 3) & 3;
      const float4 bb = *(const float4*)&bias[col];
      const f32x4 v = acc[mt][nt];
      const u16x4 d = { f2bf(fmaxf(v.x + bb.x, 0.f)), f2bf(fmaxf(v.y + bb.y, 0.f)),
                        f2bf(fmaxf(v.z + bb.z, 0.f)), f2bf(fmaxf(v.w + bb.w, 0.f)) };
      *(u16x4*)&Xs[((wn * 8 + mt) * 64 + q2 * 16 + r) * 8 + (q & 1) * 4] = d;
    }
  }
}

// ---------------------------------------------------------------------------
// Fused 3-layer MLP per (128-row batch tile, agent). 1024 threads / 16 waves.
// Xs: 128 KB frag-major [kt 16][MT 8][lane 64][e 8] (x0 -> X1 -> h in place).
// Wave wn: FULL M=128, n-slice 32 (acc[8][2]).
// k-loops are chunked (unroll-1 outer x unroll-4 inner, pointer bumps per
// chunk) so live address registers stay ~3 base pointers instead of ~16
// materialized pairs -> unified regs fit 128 (64 acc AGPR + ~40 arch VGPR),
// killing the in-loop scratch spills (the 250 MB mystery WRITE_SIZE).
// ---------------------------------------------------------------------------
__global__ __launch_bounds__(1024, 4)
void fused_mlp(const float* __restrict__ X0, const u16* __restrict__ Wsf,
               const float* __restrict__ bsh, const u16* __restrict__ W1f,
               const float* __restrict__ b1, const u16* __restrict__ W2f,
               const float* __restrict__ b2, const int* __restrict__ route,
               float* __restrict__ Out) {
  __shared__ u16 Xs[65536];                  // 128 KB

  const int tid = threadIdx.x;
  const int w = tid >> 6, l = tid & 63;
  const int r = l & 15, q = l >> 4;
  const int wn = w;                          // n-slice of 32

  // XCD-pinned: agent a on xcd = a>>2 (distinct-expert set <= 2 MB per L2)
  const int bid = blockIdx.x;                // 1024 blocks, 1024 % 8 == 0
  const int xcd = bid & 7, idx = bid >> 3;   // idx 0..127 per xcd
  const int a = (xcd << 2) | (idx >> 5);
  const int b0 = (idx & 31) << 7;            // 128-row tile
  const int rt = route[a];

  // x0 staging map: thread -> (row sm, col-quad scq); per kt-slice one float4.
  const int sm = tid >> 3, scq = tid & 7;
  const float* gx = X0 + (((size_t)(b0 + sm) * 32 + a) << 9) + (scq << 2);
  const int sdst = (((sm >> 4) << 6) + ((scq >> 1) << 4) + (sm & 15)) * 8 + (scq & 1) * 4;

  const u16* Af = Xs + l * 8;                // A frag: + kt*4096 + mt*512 (u16)

  f32x4 acc[8][2];
#pragma unroll
  for (int mt = 0; mt < 8; ++mt)
#pragma unroll
    for (int nt = 0; nt < 2; ++nt) acc[mt][nt] = (f32x4){0.f, 0.f, 0.f, 0.f};

  // ========== phase 1 (x0 conversion fused, 4-deep static pipeline) ==========
  float4 vb[4];                              // slice s lives in vb[s & 3]
  vb[0] = ntld(gx);
  vb[1] = ntld(gx + 32);
  vb[2] = ntld(gx + 64);
  vb[3] = ntld(gx + 96);
  cvt_wr(&Xs[sdst], vb[0]);                  // write slice 0
  __syncthreads();

  {
    const float* gxc = gx + 128;             // chunk-load base: slice 4c+4
    const u16* Bw0 = Wsf + (wn << 14) + l * 8;
    const u16* Bw1 = Bw0 + 8192;
    u16* Xw = Xs + sdst + 4096;              // chunk-write base: slice 4c+1
#pragma unroll 1
    for (int c = 0; c < 4; ++c) {
#pragma unroll
      for (int u = 0; u < 4; ++u) {
        // kt = 4c+u. load slice kt+4 into vb[u] (slot freed when slice 4c+u written)
        if (c < 3) vb[u] = ntld(gxc + u * 32);
        const bf16x8 bc0 = *(const bf16x8*)(Bw0 + u * 512);
        const bf16x8 bc1 = *(const bf16x8*)(Bw1 + u * 512);
#pragma unroll
        for (int mt = 0; mt < 8; ++mt) {
          const bf16x8 af = *(const bf16x8*)(Af + (c * 16384 + u * 4096) + mt * 512);
          acc[mt][0] = __builtin_amdgcn_mfma_f32_16x16x32_bf16(bc0, af, acc[mt][0], 0, 0, 0);
          acc[mt][1] = __builtin_amdgcn_mfma_f32_16x16x32_bf16(bc1, af, acc[mt][1], 0, 0, 0);
        }
        // write slice kt+1 = 4c+u+1 (loaded 4 kt ago, in vb[(u+1)&3]), then sync
        if (u < 3 || c < 3) {
          cvt_wr(Xw + u * 4096, vb[(u + 1) & 3]);
          __syncthreads();
        }
      }
      gxc += 128; Bw0 += 2048; Bw1 += 2048; Xw += 16384;
    }
  }
  __syncthreads();                           // all x0 reads done

  // hoist phase-2 first B pair: lands under phase-1 epilogue VALU
  const u16* B1 = W1f + ((size_t)rt << 18) + (wn << 14) + l * 8;
  bf16x8 bc0 = *(const bf16x8*)(B1);
  bf16x8 bc1 = *(const bf16x8*)(B1 + 8192);

  epi_relu(Xs, bsh, acc, wn, r, q);
  __syncthreads();                           // X1 visible

  // ========== phase 2: h = relu(X1 @ W1[rt]^T + b1[rt]) ==========
#pragma unroll
  for (int mt = 0; mt < 8; ++mt)
#pragma unroll
    for (int nt = 0; nt < 2; ++nt) acc[mt][nt] = (f32x4){0.f, 0.f, 0.f, 0.f};
  {
    const u16* B1c = B1;                     // chunk base (kt = 4c)
#pragma unroll 1
    for (int c = 0; c < 4; ++c) {
#pragma unroll
      for (int u = 0; u < 4; ++u) {
        // kt = 4c+u; prefetch kt+1
        bf16x8 bn0, bn1;
        const bool pf = (u < 3) || (c < 3);
        if (pf) {
          bn0 = *(const bf16x8*)(B1c + (u + 1) * 512);
          bn1 = *(const bf16x8*)(B1c + 8192 + (u + 1) * 512);
        }
#pragma unroll
        for (int mt = 0; mt < 8; ++mt) {
          const bf16x8 af = *(const bf16x8*)(Af + (c * 16384 + u * 4096) + mt * 512);
          acc[mt][0] = __builtin_amdgcn_mfma_f32_16x16x32_bf16(bc0, af, acc[mt][0], 0, 0, 0);
          acc[mt][1] = __builtin_amdgcn_mfma_f32_16x16x32_bf16(bc1, af, acc[mt][1], 0, 0, 0);
        }
        if (pf) { bc0 = bn0; bc1 = bn1; }
      }
      B1c += 2048;
    }
  }
  __syncthreads();                           // all X1 reads done
  epi_relu(Xs, b1 + (size_t)rt * 512, acc, wn, r, q);
  __syncthreads();                           // h visible

  // ========== phase 3: out = h @ W2[rt]^T + b2[rt] ==========
  {
    const int mtg = w >> 1, nt3 = w & 1;     // 128x32 out = 16 frags, 1 per wave
    const u16* Ah = Xs + (mtg << 9) + l * 8;
    const u16* B2 = W2f + ((size_t)rt << 14) + (nt3 << 13) + l * 8;
    f32x4 o = (f32x4){0.f, 0.f, 0.f, 0.f};
#pragma unroll 1
    for (int c = 0; c < 4; ++c) {
#pragma unroll
      for (int u = 0; u < 4; ++u) {
        const bf16x8 af = *(const bf16x8*)(Ah + (c * 16384 + u * 4096));
        const bf16x8 bf = *(const bf16x8*)(B2 + u * 512);
        o = __builtin_amdgcn_mfma_f32_16x16x32_bf16(bf, af, o, 0, 0, 0);
      }
      B2 += 2048;
    }
    const int col = (nt3 << 4) + (q << 2);
    const float4 bb = *(const float4*)&b2[rt * 32 + col];
    const float4 res = { o.x + bb.x, o.y + bb.y, o.z + bb.z, o.w + bb.w };
    *(float4*)&Out[(size_t)(b0 + (mtg << 4) + r) * 1024 + a * 32 + col] = res;
  }
}

// ---------------------------------------------------------------------------
extern "C" void kernel_launch(void* const* d_in, const int* in_sizes, int n_in,
                              void* d_out, int out_size, void* d_ws, size_t ws_size,
                              hipStream_t stream) {
  (void)in_sizes; (void)n_in; (void)out_size; (void)ws_size;
  const float* x0  = (const float*)d_in[0];
  const float* Wsh = (const float*)d_in[1];
  const float* bsh = (const float*)d_in[2];
  const float* W1  = (const float*)d_in[3];
  const float* b1  = (const float*)d_in[4];
  const float* W2  = (const float*)d_in[5];
  const float* b2  = (const float*)d_in[6];
  const int* route = (const int*)d_in[7];
  float* out = (float*)d_out;

  char* ws = (char*)d_ws;
  u16* Wsf = (u16*)(ws + 0);                      // 512*512*2    = 512 KB  frag-major
  u16* W1f = (u16*)(ws + 524288);                 // 32*512*512*2 = 16 MB   frag-major, source-indexed
  u16* W2f = (u16*)(ws + 524288 + 16777216);      // 32*32*512*2  = 1 MB    frag-major, source-indexed

  frag_cvt<<<dim3(4, 32, 1),  256, 0, stream>>>(Wsh, nullptr, Wsf, 512, 512);
  frag_cvt<<<dim3(4, 32, 32), 256, 0, stream>>>(W1, route, W1f, 512, 512);   // only used experts
  frag_cvt<<<dim3(4, 2, 32),  256, 0, stream>>>(W2, route, W2f, 512, 32);    // only used experts
  fused_mlp<<<dim3(1024), 1024, 0, stream>>>(x0, Wsf, bsh, W1f, b1, W2f, b2, route, out);
}